// Round 1
// baseline (3158.724 us; speedup 1.0000x reference)
//
#include <hip/hip_runtime.h>
#include <hip/hip_bf16.h>
#include <math.h>

// Problem constants
#define Bq 128
#define Nq 100
#define Dq 2048
#define Hq 1024
#define Oq 1600
#define Aq 400
#define Lq 2048
#define Mq (Bq * Nq)   // 12800 rows

// ---------------- fp32 tiled GEMM: C = act(A @ W + bias) ----------------
// A: M x K row-major, W: K x N row-major, C: M x N row-major.
// M must be a multiple of 128 (12800 ok), K a multiple of 8. N guarded.
#define BM 128
#define BN 128
#define BK 8
#define TM 8
#define TN 8

__global__ __launch_bounds__(256) void gemm_bias_act(
    const float* __restrict__ A, const float* __restrict__ W,
    const float* __restrict__ bias, float* __restrict__ C,
    int M, int K, int N, int do_relu)
{
    __shared__ float As[BK][BM];   // transposed A tile: As[k][m]
    __shared__ float Ws[BK][BN];

    const int bm = blockIdx.y * BM;
    const int bn = blockIdx.x * BN;
    const int tid = threadIdx.x;           // 0..255
    const int tx = tid & 15;               // 16 across N
    const int ty = tid >> 4;               // 16 across M

    // A-tile load mapping: 128 rows x 8 k, float4 along K
    const int arow = tid >> 1;             // 0..127
    const int acol = (tid & 1) << 2;       // 0 or 4
    // W-tile load mapping: 8 k x 128 cols, float4 along N
    const int wrow = tid >> 5;             // 0..7
    const int wcol = (tid & 31) << 2;      // 0..124

    float acc[TM][TN];
#pragma unroll
    for (int i = 0; i < TM; i++)
#pragma unroll
        for (int j = 0; j < TN; j++) acc[i][j] = 0.f;

    const float* Aptr = A + (size_t)(bm + arow) * K + acol;
    const bool wok = (bn + wcol) < N;      // N % 4 == 0 for all layers

    for (int k0 = 0; k0 < K; k0 += BK) {
        float4 av = *(const float4*)(Aptr + k0);
        float4 wv = make_float4(0.f, 0.f, 0.f, 0.f);
        if (wok) wv = *(const float4*)(W + (size_t)(k0 + wrow) * N + bn + wcol);

        As[acol + 0][arow] = av.x;
        As[acol + 1][arow] = av.y;
        As[acol + 2][arow] = av.z;
        As[acol + 3][arow] = av.w;
        *(float4*)&Ws[wrow][wcol] = wv;
        __syncthreads();

#pragma unroll
        for (int kk = 0; kk < BK; kk++) {
            float a[TM], b[TN];
            *(float4*)&a[0] = *(const float4*)&As[kk][ty * 8];
            *(float4*)&a[4] = *(const float4*)&As[kk][ty * 8 + 4];
            *(float4*)&b[0] = *(const float4*)&Ws[kk][tx * 8];
            *(float4*)&b[4] = *(const float4*)&Ws[kk][tx * 8 + 4];
#pragma unroll
            for (int i = 0; i < TM; i++)
#pragma unroll
                for (int j = 0; j < TN; j++)
                    acc[i][j] = fmaf(a[i], b[j], acc[i][j]);
        }
        __syncthreads();
    }

    // epilogue: bias + optional relu, float4 stores, column-guarded
#pragma unroll
    for (int i = 0; i < TM; i++) {
        const int r = bm + ty * 8 + i;
        float* Crow = C + (size_t)r * N;
#pragma unroll
        for (int j0 = 0; j0 < TN; j0 += 4) {
            const int c = bn + tx * 8 + j0;
            if (c < N) {   // c and N are multiples of 4
                float4 v;
                v.x = acc[i][j0 + 0] + bias[c + 0];
                v.y = acc[i][j0 + 1] + bias[c + 1];
                v.z = acc[i][j0 + 2] + bias[c + 2];
                v.w = acc[i][j0 + 3] + bias[c + 3];
                if (do_relu) {
                    v.x = fmaxf(v.x, 0.f);
                    v.y = fmaxf(v.y, 0.f);
                    v.z = fmaxf(v.z, 0.f);
                    v.w = fmaxf(v.w, 0.f);
                }
                *(float4*)(Crow + c) = v;
            }
        }
    }
}

// ------------- per-row softmax stats: rowmax and sum(exp(z-max)) -------------
__global__ void softmax_stats(const float* __restrict__ Z, int ncols,
                              float* __restrict__ mx, float* __restrict__ sm)
{
    const int r = blockIdx.x;
    const float* row = Z + (size_t)r * ncols;
    __shared__ float red[256];
    float m = -INFINITY;
    for (int c = threadIdx.x; c < ncols; c += 256) m = fmaxf(m, row[c]);
    red[threadIdx.x] = m;
    __syncthreads();
    for (int s = 128; s > 0; s >>= 1) {
        if (threadIdx.x < s) red[threadIdx.x] = fmaxf(red[threadIdx.x], red[threadIdx.x + s]);
        __syncthreads();
    }
    m = red[0];
    __syncthreads();
    float su = 0.f;
    for (int c = threadIdx.x; c < ncols; c += 256) su += expf(row[c] - m);
    red[threadIdx.x] = su;
    __syncthreads();
    for (int s = 128; s > 0; s >>= 1) {
        if (threadIdx.x < s) red[threadIdx.x] += red[threadIdx.x + s];
        __syncthreads();
    }
    if (threadIdx.x == 0) { mx[r] = m; sm[r] = red[0]; }
}

// ------------- per-label argmax over n of p_obj * p_att -------------
__global__ void argmax_kernel(
    const float* __restrict__ Zo, const float* __restrict__ Za,
    const float* __restrict__ mxo, const float* __restrict__ smo,
    const float* __restrict__ mxa, const float* __restrict__ sma,
    const int* __restrict__ label_img, const int* __restrict__ num_descs,
    const int* __restrict__ obj_labels, const int* __restrict__ att_labels,
    int* __restrict__ desc)
{
    const int l = blockIdx.x;
    const int b = label_img[l];
    const int oc = obj_labels[l];
    const int ac = att_labels[l];
    const int nd = num_descs[b];
    const int n = threadIdx.x;   // blockDim 128

    float score = -INFINITY;
    if (n < Nq && n < nd) {
        const int r = b * Nq + n;
        const float po = expf(Zo[(size_t)r * Oq + oc] - mxo[r]) / smo[r];
        const float pa = expf(Za[(size_t)r * Aq + ac] - mxa[r]) / sma[r];
        score = po * pa;   // same math as reference; ordering-preserving
    }
    __shared__ float ss[128];
    __shared__ int   si[128];
    ss[n] = score;
    si[n] = n;
    __syncthreads();
    for (int s = 64; s > 0; s >>= 1) {
        if (n < s) {
            const float s2 = ss[n + s];
            const int   i2 = si[n + s];
            // jnp.argmax picks the FIRST max; all -inf -> index 0
            if (s2 > ss[n] || (s2 == ss[n] && i2 < si[n])) { ss[n] = s2; si[n] = i2; }
        }
        __syncthreads();
    }
    if (n == 0) desc[l] = si[0];
}

// ------------- gather output rows: softmax(z[b, desc, :]) -------------
__global__ void gather_out(
    const float* __restrict__ Zo, const float* __restrict__ Za,
    const float* __restrict__ mxo, const float* __restrict__ smo,
    const float* __restrict__ mxa, const float* __restrict__ sma,
    const int* __restrict__ label_img, const int* __restrict__ desc,
    float* __restrict__ out)
{
    const int l = blockIdx.x;
    const int b = label_img[l];
    const int r = b * Nq + desc[l];

    const float mo = mxo[r], so = smo[r];
    const float* zo = Zo + (size_t)r * Oq;
    float* oo = out + (size_t)l * Oq;
    for (int c = threadIdx.x; c < Oq; c += blockDim.x)
        oo[c] = expf(zo[c] - mo) / so;

    const float ma = mxa[r], sa = sma[r];
    const float* za = Za + (size_t)r * Aq;
    float* oa = out + (size_t)Lq * Oq + (size_t)l * Aq;
    for (int c = threadIdx.x; c < Aq; c += blockDim.x)
        oa[c] = expf(za[c] - ma) / sa;
}

extern "C" void kernel_launch(void* const* d_in, const int* in_sizes, int n_in,
                              void* d_out, int out_size, void* d_ws, size_t ws_size,
                              hipStream_t stream)
{
    const float* x          = (const float*)d_in[0];
    const int*   num_descs  = (const int*)d_in[1];
    const int*   label_img  = (const int*)d_in[2];
    const int*   obj_labels = (const int*)d_in[3];
    const int*   att_labels = (const int*)d_in[4];
    const float* w1o = (const float*)d_in[5];  const float* b1o = (const float*)d_in[6];
    const float* w2o = (const float*)d_in[7];  const float* b2o = (const float*)d_in[8];
    const float* w3o = (const float*)d_in[9];  const float* b3o = (const float*)d_in[10];
    const float* w1a = (const float*)d_in[11]; const float* b1a = (const float*)d_in[12];
    const float* w2a = (const float*)d_in[13]; const float* b2a = (const float*)d_in[14];
    const float* w3a = (const float*)d_in[15]; const float* b3a = (const float*)d_in[16];
    float* out = (float*)d_out;

    // workspace layout (floats); total ~65.0M floats = 260 MB
    float* ws  = (float*)d_ws;
    float* h1  = ws;                              // 12800*1024
    float* h2o = h1  + (size_t)Mq * Hq;           // 12800*1024
    float* h2a = h2o + (size_t)Mq * Hq;           // 12800*1024
    float* z3o = h2a + (size_t)Mq * Hq;           // 12800*1600
    float* z3a = z3o + (size_t)Mq * Oq;           // 12800*400
    float* mxo = z3a + (size_t)Mq * Aq;
    float* smo = mxo + Mq;
    float* mxa = smo + Mq;
    float* sma = mxa + Mq;
    int*   desc = (int*)(sma + Mq);

    const dim3 blk(256);
    const dim3 gl1(Hq / BN, Mq / BM);   // (8, 100)
    const dim3 gl2(Hq / BN, Mq / BM);   // (8, 100)
    const dim3 g3o((Oq + BN - 1) / BN, Mq / BM); // (13, 100)
    const dim3 g3a((Aq + BN - 1) / BN, Mq / BM); // (4, 100)

    // obj branch
    gemm_bias_act<<<gl1, blk, 0, stream>>>(x,   w1o, b1o, h1,  Mq, Dq, Hq, 1);
    gemm_bias_act<<<gl2, blk, 0, stream>>>(h1,  w2o, b2o, h2o, Mq, Hq, Hq, 1);
    gemm_bias_act<<<g3o, blk, 0, stream>>>(h2o, w3o, b3o, z3o, Mq, Hq, Oq, 0);
    // att branch (reuses h1)
    gemm_bias_act<<<gl1, blk, 0, stream>>>(x,   w1a, b1a, h1,  Mq, Dq, Hq, 1);
    gemm_bias_act<<<gl2, blk, 0, stream>>>(h1,  w2a, b2a, h2a, Mq, Hq, Hq, 1);
    gemm_bias_act<<<g3a, blk, 0, stream>>>(h2a, w3a, b3a, z3a, Mq, Hq, Aq, 0);

    softmax_stats<<<Mq, 256, 0, stream>>>(z3o, Oq, mxo, smo);
    softmax_stats<<<Mq, 256, 0, stream>>>(z3a, Aq, mxa, sma);

    argmax_kernel<<<Lq, 128, 0, stream>>>(z3o, z3a, mxo, smo, mxa, sma,
                                          label_img, num_descs, obj_labels, att_labels, desc);

    gather_out<<<Lq, 256, 0, stream>>>(z3o, z3a, mxo, smo, mxa, sma,
                                       label_img, desc, out);
}

// Round 2
// 1182.222 us; speedup vs baseline: 2.6719x; 2.6719x over previous
//
#include <hip/hip_runtime.h>
#include <hip/hip_bf16.h>
#include <math.h>

// Problem constants
#define Bq 128
#define Nq 100
#define Dq 2048
#define Hq 1024
#define Oq 1600
#define Aq 400
#define Lq 2048
#define Mq (Bq * Nq)     // 12800 rows
#define OqP 1664         // Oq padded to multiple of 128
#define AqP 512          // Aq padded to multiple of 128

typedef __attribute__((ext_vector_type(8))) short bf16x8;
typedef __attribute__((ext_vector_type(4))) float f32x4;
typedef unsigned short ushort;

// ---------------- helpers ----------------
__device__ __forceinline__ void split1(float v, ushort& h, ushort& l) {
    __hip_bfloat16 bh = __float2bfloat16(v);          // RNE
    float fh = __bfloat162float(bh);
    __hip_bfloat16 bl = __float2bfloat16(v - fh);     // exact residual, then RNE
    h = __builtin_bit_cast(ushort, bh);
    l = __builtin_bit_cast(ushort, bl);
}

__device__ __forceinline__ void gl_lds16(const ushort* g, ushort* lds) {
    __builtin_amdgcn_global_load_lds(
        (const __attribute__((address_space(1))) unsigned int*)g,
        (__attribute__((address_space(3))) unsigned int*)lds,
        16, 0, 0);
}

// ---------------- split x into hi/lo bf16 ----------------
__global__ void split_f32(const float* __restrict__ in, ushort* __restrict__ hi,
                          ushort* __restrict__ lo, long n)
{
    long i = ((long)blockIdx.x * blockDim.x + threadIdx.x) * 8;
    if (i >= n) return;
    float4 v0 = *(const float4*)(in + i);
    float4 v1 = *(const float4*)(in + i + 4);
    float v[8] = {v0.x, v0.y, v0.z, v0.w, v1.x, v1.y, v1.z, v1.w};
    ushort h[8], l[8];
#pragma unroll
    for (int j = 0; j < 8; j++) split1(v[j], h[j], l[j]);
    *(bf16x8*)(hi + i) = *(bf16x8*)h;
    *(bf16x8*)(lo + i) = *(bf16x8*)l;
}

// ------- transpose + split weights: W[K][N] -> Wt_hi/lo[Npad][K] (zero pad) -------
__global__ void tsplit(const float* __restrict__ W, ushort* __restrict__ Th,
                       ushort* __restrict__ Tl, int K, int N)
{
    __shared__ float t[32][33];
    const int bn = blockIdx.x * 32;
    const int bk = blockIdx.y * 32;
    const int tx = threadIdx.x & 31, ty = threadIdx.x >> 5;   // ty 0..7
#pragma unroll
    for (int i = 0; i < 4; i++) {
        const int k = bk + ty + i * 8, n = bn + tx;
        t[ty + i * 8][tx] = (n < N) ? W[(size_t)k * N + n] : 0.f;
    }
    __syncthreads();
#pragma unroll
    for (int i = 0; i < 4; i++) {
        const int n = bn + ty + i * 8, k = bk + tx;
        const float v = t[tx][ty + i * 8];
        ushort h, l;
        split1(v, h, l);
        Th[(size_t)n * K + k] = h;
        Tl[(size_t)n * K + k] = l;
    }
}

// ---------------- split-bf16 MFMA GEMM ----------------
// C = act(A @ W + bias) with A=[M][K] split hi/lo, Wt=[Npad][K] split hi/lo.
// a*w ~= ah*wh + ah*wl + al*wh (3 MFMAs, fp32 accumulate).
// mode 1: relu + write split bf16 (Chh/Cll). mode 0: write fp32 (Cf).
__global__ __launch_bounds__(256) void gemm_split(
    const ushort* __restrict__ Ah, const ushort* __restrict__ Al,
    const ushort* __restrict__ Bh, const ushort* __restrict__ Bl,
    const float* __restrict__ bias, float* __restrict__ Cf,
    ushort* __restrict__ Chh, ushort* __restrict__ Cll,
    int M, int K, int N, int mode)
{
    __shared__ __align__(16) ushort sAh[128 * 32];
    __shared__ __align__(16) ushort sAl[128 * 32];
    __shared__ __align__(16) ushort sBh[128 * 32];
    __shared__ __align__(16) ushort sBl[128 * 32];

    const int tid  = threadIdx.x;
    const int wave = tid >> 6;           // 0..3
    const int lane = tid & 63;
    const int wm = (wave >> 1) * 64;     // wave's 64x64 quadrant
    const int wn = (wave & 1) * 64;
    const int lm   = lane & 15;
    const int quad = lane >> 4;          // 0..3

    const int bm = blockIdx.y * 128;
    const int bn = blockIdx.x * 128;     // within Npad

    // staging: per wave, 2 instrs per buffer; instr q covers rows wave*32+q*16
    const int srow = wave * 32 + (lane >> 2);       // 0..127 (q=0 half)
    const int scol = (lane & 3) * 8;                // k element offset
    const ushort* gAh = Ah + (size_t)(bm + srow) * K + scol;
    const ushort* gAl = Al + (size_t)(bm + srow) * K + scol;
    const ushort* gBh = Bh + (size_t)(bn + srow) * K + scol;
    const ushort* gBl = Bl + (size_t)(bn + srow) * K + scol;
    const size_t rstep = (size_t)16 * K;            // q=1: +16 rows
    ushort* lAh0 = &sAh[(wave * 32) * 32];  ushort* lAh1 = &sAh[(wave * 32 + 16) * 32];
    ushort* lAl0 = &sAl[(wave * 32) * 32];  ushort* lAl1 = &sAl[(wave * 32 + 16) * 32];
    ushort* lBh0 = &sBh[(wave * 32) * 32];  ushort* lBh1 = &sBh[(wave * 32 + 16) * 32];
    ushort* lBl0 = &sBl[(wave * 32) * 32];  ushort* lBl1 = &sBl[(wave * 32 + 16) * 32];

    // fragment read offsets (elements) per i/j
    int aoff[4], boff[4];
#pragma unroll
    for (int i = 0; i < 4; i++) {
        aoff[i] = (wm + i * 16 + lm) * 32 + quad * 8;
        boff[i] = (wn + i * 16 + lm) * 32 + quad * 8;
    }

    f32x4 acc[4][4] = {};

    for (int k0 = 0; k0 < K; k0 += 32) {
        gl_lds16(gAh + k0, lAh0);  gl_lds16(gAh + rstep + k0, lAh1);
        gl_lds16(gAl + k0, lAl0);  gl_lds16(gAl + rstep + k0, lAl1);
        gl_lds16(gBh + k0, lBh0);  gl_lds16(gBh + rstep + k0, lBh1);
        gl_lds16(gBl + k0, lBl0);  gl_lds16(gBl + rstep + k0, lBl1);
        __syncthreads();

        bf16x8 ah[4], al[4], bh[4], bl[4];
#pragma unroll
        for (int i = 0; i < 4; i++) {
            ah[i] = *(const bf16x8*)&sAh[aoff[i]];
            al[i] = *(const bf16x8*)&sAl[aoff[i]];
            bh[i] = *(const bf16x8*)&sBh[boff[i]];
            bl[i] = *(const bf16x8*)&sBl[boff[i]];
        }
#pragma unroll
        for (int i = 0; i < 4; i++)
#pragma unroll
            for (int j = 0; j < 4; j++) {
                acc[i][j] = __builtin_amdgcn_mfma_f32_16x16x32_bf16(ah[i], bh[j], acc[i][j], 0, 0, 0);
                acc[i][j] = __builtin_amdgcn_mfma_f32_16x16x32_bf16(ah[i], bl[j], acc[i][j], 0, 0, 0);
                acc[i][j] = __builtin_amdgcn_mfma_f32_16x16x32_bf16(al[i], bh[j], acc[i][j], 0, 0, 0);
            }
        __syncthreads();
    }

    // epilogue: C/D layout col=lane&15, row=quad*4+reg
#pragma unroll
    for (int j = 0; j < 4; j++) {
        const int col = bn + wn + j * 16 + lm;
        if (col < N) {
            const float bv = bias[col];
#pragma unroll
            for (int i = 0; i < 4; i++) {
#pragma unroll
                for (int r = 0; r < 4; r++) {
                    const int row = bm + wm + i * 16 + quad * 4 + r;
                    float v = acc[i][j][r] + bv;
                    if (mode == 1) {
                        v = fmaxf(v, 0.f);
                        ushort h, l;
                        split1(v, h, l);
                        Chh[(size_t)row * N + col] = h;
                        Cll[(size_t)row * N + col] = l;
                    } else {
                        Cf[(size_t)row * N + col] = v;
                    }
                }
            }
        }
    }
}

// ------------- per-row softmax stats: rowmax and sum(exp(z-max)) -------------
__global__ void softmax_stats(const float* __restrict__ Z, int ncols,
                              float* __restrict__ mx, float* __restrict__ sm)
{
    const int r = blockIdx.x;
    const float* row = Z + (size_t)r * ncols;
    __shared__ float red[256];
    float m = -INFINITY;
    for (int c = threadIdx.x; c < ncols; c += 256) m = fmaxf(m, row[c]);
    red[threadIdx.x] = m;
    __syncthreads();
    for (int s = 128; s > 0; s >>= 1) {
        if (threadIdx.x < s) red[threadIdx.x] = fmaxf(red[threadIdx.x], red[threadIdx.x + s]);
        __syncthreads();
    }
    m = red[0];
    __syncthreads();
    float su = 0.f;
    for (int c = threadIdx.x; c < ncols; c += 256) su += expf(row[c] - m);
    red[threadIdx.x] = su;
    __syncthreads();
    for (int s = 128; s > 0; s >>= 1) {
        if (threadIdx.x < s) red[threadIdx.x] += red[threadIdx.x + s];
        __syncthreads();
    }
    if (threadIdx.x == 0) { mx[r] = m; sm[r] = red[0]; }
}

// ------------- per-label argmax over n of p_obj * p_att -------------
__global__ void argmax_kernel(
    const float* __restrict__ Zo, const float* __restrict__ Za,
    const float* __restrict__ mxo, const float* __restrict__ smo,
    const float* __restrict__ mxa, const float* __restrict__ sma,
    const int* __restrict__ label_img, const int* __restrict__ num_descs,
    const int* __restrict__ obj_labels, const int* __restrict__ att_labels,
    int* __restrict__ desc)
{
    const int l = blockIdx.x;
    const int b = label_img[l];
    const int oc = obj_labels[l];
    const int ac = att_labels[l];
    const int nd = num_descs[b];
    const int n = threadIdx.x;   // blockDim 128

    float score = -INFINITY;
    if (n < Nq && n < nd) {
        const int r = b * Nq + n;
        const float po = expf(Zo[(size_t)r * Oq + oc] - mxo[r]) / smo[r];
        const float pa = expf(Za[(size_t)r * Aq + ac] - mxa[r]) / sma[r];
        score = po * pa;
    }
    __shared__ float ss[128];
    __shared__ int   si[128];
    ss[n] = score;
    si[n] = n;
    __syncthreads();
    for (int s = 64; s > 0; s >>= 1) {
        if (n < s) {
            const float s2 = ss[n + s];
            const int   i2 = si[n + s];
            if (s2 > ss[n] || (s2 == ss[n] && i2 < si[n])) { ss[n] = s2; si[n] = i2; }
        }
        __syncthreads();
    }
    if (n == 0) desc[l] = si[0];
}

// ------------- gather output rows: softmax(z[b, desc, :]) -------------
__global__ void gather_out(
    const float* __restrict__ Zo, const float* __restrict__ Za,
    const float* __restrict__ mxo, const float* __restrict__ smo,
    const float* __restrict__ mxa, const float* __restrict__ sma,
    const int* __restrict__ label_img, const int* __restrict__ desc,
    float* __restrict__ out)
{
    const int l = blockIdx.x;
    const int b = label_img[l];
    const int r = b * Nq + desc[l];

    const float mo = mxo[r], so = smo[r];
    const float* zo = Zo + (size_t)r * Oq;
    float* oo = out + (size_t)l * Oq;
    for (int c = threadIdx.x; c < Oq; c += blockDim.x)
        oo[c] = expf(zo[c] - mo) / so;

    const float ma = mxa[r], sa = sma[r];
    const float* za = Za + (size_t)r * Aq;
    float* oa = out + (size_t)Lq * Oq + (size_t)l * Aq;
    for (int c = threadIdx.x; c < Aq; c += blockDim.x)
        oa[c] = expf(za[c] - ma) / sa;
}

extern "C" void kernel_launch(void* const* d_in, const int* in_sizes, int n_in,
                              void* d_out, int out_size, void* d_ws, size_t ws_size,
                              hipStream_t stream)
{
    const float* x          = (const float*)d_in[0];
    const int*   num_descs  = (const int*)d_in[1];
    const int*   label_img  = (const int*)d_in[2];
    const int*   obj_labels = (const int*)d_in[3];
    const int*   att_labels = (const int*)d_in[4];
    const float* w1o = (const float*)d_in[5];  const float* b1o = (const float*)d_in[6];
    const float* w2o = (const float*)d_in[7];  const float* b2o = (const float*)d_in[8];
    const float* w3o = (const float*)d_in[9];  const float* b3o = (const float*)d_in[10];
    const float* w1a = (const float*)d_in[11]; const float* b1a = (const float*)d_in[12];
    const float* w2a = (const float*)d_in[13]; const float* b2a = (const float*)d_in[14];
    const float* w3a = (const float*)d_in[15]; const float* b3a = (const float*)d_in[16];
    float* out = (float*)d_out;

    // ---- workspace carve (all chunks 16B-aligned) ----
    char* p = (char*)d_ws;
    auto carve_us = [&](size_t nelem) { ushort* q = (ushort*)p; p += nelem * 2; return q; };
    auto carve_f  = [&](size_t nelem) { float*  q = (float*)p;  p += nelem * 4; return q; };

    ushort* xh = carve_us((size_t)Mq * Dq);
    ushort* xl = carve_us((size_t)Mq * Dq);
    ushort* w1oth = carve_us((size_t)Hq * Dq);  ushort* w1otl = carve_us((size_t)Hq * Dq);
    ushort* w2oth = carve_us((size_t)Hq * Hq);  ushort* w2otl = carve_us((size_t)Hq * Hq);
    ushort* w3oth = carve_us((size_t)OqP * Hq); ushort* w3otl = carve_us((size_t)OqP * Hq);
    ushort* w1ath = carve_us((size_t)Hq * Dq);  ushort* w1atl = carve_us((size_t)Hq * Dq);
    ushort* w2ath = carve_us((size_t)Hq * Hq);  ushort* w2atl = carve_us((size_t)Hq * Hq);
    ushort* w3ath = carve_us((size_t)AqP * Hq); ushort* w3atl = carve_us((size_t)AqP * Hq);
    ushort* h1h = carve_us((size_t)Mq * Hq);    ushort* h1l = carve_us((size_t)Mq * Hq);
    ushort* h2h = carve_us((size_t)Mq * Hq);    ushort* h2l = carve_us((size_t)Mq * Hq);
    float* z3o = carve_f((size_t)Mq * Oq);
    float* z3a = carve_f((size_t)Mq * Aq);
    float* mxo = carve_f(Mq); float* smo = carve_f(Mq);
    float* mxa = carve_f(Mq); float* sma = carve_f(Mq);
    int*   desc = (int*)carve_f(Lq);

    // ---- preprocessing: split x, transpose+split weights ----
    split_f32<<<((size_t)Mq * Dq / 8 + 255) / 256, 256, 0, stream>>>(x, xh, xl, (long)Mq * Dq);
    tsplit<<<dim3(Hq / 32, Dq / 32), 256, 0, stream>>>(w1o, w1oth, w1otl, Dq, Hq);
    tsplit<<<dim3(Hq / 32, Hq / 32), 256, 0, stream>>>(w2o, w2oth, w2otl, Hq, Hq);
    tsplit<<<dim3(OqP / 32, Hq / 32), 256, 0, stream>>>(w3o, w3oth, w3otl, Hq, Oq);
    tsplit<<<dim3(Hq / 32, Dq / 32), 256, 0, stream>>>(w1a, w1ath, w1atl, Dq, Hq);
    tsplit<<<dim3(Hq / 32, Hq / 32), 256, 0, stream>>>(w2a, w2ath, w2atl, Hq, Hq);
    tsplit<<<dim3(AqP / 32, Hq / 32), 256, 0, stream>>>(w3a, w3ath, w3atl, Hq, Aq);

    const dim3 blk(256);
    // ---- obj branch ----
    gemm_split<<<dim3(Hq / 128, Mq / 128), blk, 0, stream>>>(
        xh, xl, w1oth, w1otl, b1o, nullptr, h1h, h1l, Mq, Dq, Hq, 1);
    gemm_split<<<dim3(Hq / 128, Mq / 128), blk, 0, stream>>>(
        h1h, h1l, w2oth, w2otl, b2o, nullptr, h2h, h2l, Mq, Hq, Hq, 1);
    gemm_split<<<dim3(OqP / 128, Mq / 128), blk, 0, stream>>>(
        h2h, h2l, w3oth, w3otl, b3o, z3o, nullptr, nullptr, Mq, Hq, Oq, 0);
    // ---- att branch (reuses h1/h2) ----
    gemm_split<<<dim3(Hq / 128, Mq / 128), blk, 0, stream>>>(
        xh, xl, w1ath, w1atl, b1a, nullptr, h1h, h1l, Mq, Dq, Hq, 1);
    gemm_split<<<dim3(Hq / 128, Mq / 128), blk, 0, stream>>>(
        h1h, h1l, w2ath, w2atl, b2a, nullptr, h2h, h2l, Mq, Hq, Hq, 1);
    gemm_split<<<dim3(AqP / 128, Mq / 128), blk, 0, stream>>>(
        h2h, h2l, w3ath, w3atl, b3a, z3a, nullptr, nullptr, Mq, Hq, Aq, 0);

    // ---- epilogue ----
    softmax_stats<<<Mq, 256, 0, stream>>>(z3o, Oq, mxo, smo);
    softmax_stats<<<Mq, 256, 0, stream>>>(z3a, Aq, mxa, sma);
    argmax_kernel<<<Lq, 128, 0, stream>>>(z3o, z3a, mxo, smo, mxa, sma,
                                          label_img, num_descs, obj_labels, att_labels, desc);
    gather_out<<<Lq, 256, 0, stream>>>(z3o, z3a, mxo, smo, mxa, sma,
                                       label_img, desc, out);
}

// Round 3
// 679.486 us; speedup vs baseline: 4.6487x; 1.7399x over previous
//
#include <hip/hip_runtime.h>
#include <hip/hip_bf16.h>
#include <math.h>

// Problem constants
#define Bq 128
#define Nq 100
#define Dq 2048
#define Hq 1024
#define Oq 1600
#define Aq 400
#define Lq 2048
#define Mq (Bq * Nq)     // 12800 rows max
#define OqP 1664         // Oq padded to multiple of 128
#define AqP 512          // Aq padded to multiple of 128

typedef __attribute__((ext_vector_type(8))) short bf16x8;
typedef __attribute__((ext_vector_type(4))) float f32x4;
typedef unsigned short ushort;

// ---------------- helpers ----------------
__device__ __forceinline__ void split1(float v, ushort& h, ushort& l) {
    __hip_bfloat16 bh = __float2bfloat16(v);          // RNE
    float fh = __bfloat162float(bh);
    __hip_bfloat16 bl = __float2bfloat16(v - fh);     // exact residual, then RNE
    h = __builtin_bit_cast(ushort, bh);
    l = __builtin_bit_cast(ushort, bl);
}

__device__ __forceinline__ void gl_lds16(const ushort* g, ushort* lds) {
    __builtin_amdgcn_global_load_lds(
        (const __attribute__((address_space(1))) unsigned int*)g,
        (__attribute__((address_space(3))) unsigned int*)lds,
        16, 0, 0);
}

// ------------- row compaction: offsets + rowmap -------------
// cnt[b] = max(num_descs[b],1)  (rows >= num_descs never affect outputs;
// row 0 kept when nd==0 because argmax of all -inf returns 0)
__global__ void build_offsets(const int* __restrict__ num_descs,
                              int* __restrict__ off, int* __restrict__ mc,
                              int* __restrict__ rowmap)
{
    __shared__ int cnt[Bq];
    __shared__ int offs[Bq + 1];
    const int t = threadIdx.x;            // 0..127
    int nd = num_descs[t];
    nd = nd < 0 ? 0 : (nd > Nq ? Nq : nd);
    const int c = nd < 1 ? 1 : nd;
    cnt[t] = c;
    __syncthreads();
    if (t == 0) {
        int s = 0;
        for (int i = 0; i < Bq; i++) { offs[i] = s; s += cnt[i]; }
        offs[Bq] = s;
        mc[0] = s;                          // Mc
        mc[1] = (s + 127) & ~127;           // McPad
    }
    __syncthreads();
    off[t] = offs[t];
    for (int i = t; i < Mq; i += Bq) rowmap[i] = -1;
    __syncthreads();
    const int o = offs[t];
    for (int n = 0; n < c; n++) rowmap[o + n] = t * Nq + n;
}

// ---------------- gather + split x into compact hi/lo bf16 ----------------
__global__ void split_compact(const float* __restrict__ x,
                              const int* __restrict__ rowmap,
                              const int* __restrict__ mc,
                              ushort* __restrict__ hi, ushort* __restrict__ lo)
{
    const long i = ((long)blockIdx.x * blockDim.x + threadIdx.x) * 8;
    const int c = (int)(i >> 11);          // compact row (Dq=2048)
    if (c >= mc[1]) return;
    const int orig = (c < mc[0]) ? rowmap[c] : -1;
    ushort h[8], l[8];
    if (orig < 0) {
#pragma unroll
        for (int j = 0; j < 8; j++) { h[j] = 0; l[j] = 0; }
    } else {
        const float* src = x + (size_t)orig * Dq + (i & 2047);
        float4 v0 = *(const float4*)(src);
        float4 v1 = *(const float4*)(src + 4);
        float v[8] = {v0.x, v0.y, v0.z, v0.w, v1.x, v1.y, v1.z, v1.w};
#pragma unroll
        for (int j = 0; j < 8; j++) split1(v[j], h[j], l[j]);
    }
    *(bf16x8*)(hi + i) = *(bf16x8*)h;
    *(bf16x8*)(lo + i) = *(bf16x8*)l;
}

// ------- transpose + split weights: W[K][N] -> Wt_hi/lo[Npad][K] (zero pad) -------
__global__ void tsplit(const float* __restrict__ W, ushort* __restrict__ Th,
                       ushort* __restrict__ Tl, int K, int N)
{
    __shared__ float t[32][33];
    const int bn = blockIdx.x * 32;
    const int bk = blockIdx.y * 32;
    const int tx = threadIdx.x & 31, ty = threadIdx.x >> 5;   // ty 0..7
#pragma unroll
    for (int i = 0; i < 4; i++) {
        const int k = bk + ty + i * 8, n = bn + tx;
        t[ty + i * 8][tx] = (n < N) ? W[(size_t)k * N + n] : 0.f;
    }
    __syncthreads();
#pragma unroll
    for (int i = 0; i < 4; i++) {
        const int n = bn + ty + i * 8, k = bk + tx;
        const float v = t[tx][ty + i * 8];
        ushort h, l;
        split1(v, h, l);
        Th[(size_t)n * K + k] = h;
        Tl[(size_t)n * K + k] = l;
    }
}

// ---------------- split-bf16 MFMA GEMM (branch-fused via blockIdx.z) ----------------
struct GArgs {
    const ushort* Ah; const ushort* Al;     // A [McPad][lda] split
    const ushort* Bh; const ushort* Bl;     // B [Npad][K] split (transposed)
    const float* bias;
    float* Cf; ushort* Ch; ushort* Cl;      // outputs
    int K, Npad, Nreal, lda, ldc, mode;     // mode 1: relu+split write; 0: fp32 write
};

__global__ __launch_bounds__(256) void gemm_split(GArgs g0, GArgs g1,
                                                  const int* __restrict__ mcp)
{
    const GArgs g = (blockIdx.z == 0) ? g0 : g1;
    const int bm = blockIdx.y * 128;
    const int bn = blockIdx.x * 128;
    if (bn >= g.Npad) return;
    if (bm >= mcp[1]) return;

    __shared__ __align__(16) ushort sAh[128 * 32];
    __shared__ __align__(16) ushort sAl[128 * 32];
    __shared__ __align__(16) ushort sBh[128 * 32];
    __shared__ __align__(16) ushort sBl[128 * 32];

    const int tid  = threadIdx.x;
    const int wave = tid >> 6;           // 0..3
    const int lane = tid & 63;
    const int wm = (wave >> 1) * 64;     // wave's 64x64 quadrant
    const int wn = (wave & 1) * 64;
    const int lm   = lane & 15;
    const int quad = lane >> 4;          // 0..3

    // staging: per wave, 2 instrs per buffer; instr q covers rows wave*32+q*16
    const int srow = wave * 32 + (lane >> 2);       // 0..127 (q=0 half)
    const int scol = (lane & 3) * 8;                // k element offset
    const ushort* gAh = g.Ah + (size_t)(bm + srow) * g.lda + scol;
    const ushort* gAl = g.Al + (size_t)(bm + srow) * g.lda + scol;
    const ushort* gBh = g.Bh + (size_t)(bn + srow) * g.K + scol;
    const ushort* gBl = g.Bl + (size_t)(bn + srow) * g.K + scol;
    const size_t rstepA = (size_t)16 * g.lda;
    const size_t rstepB = (size_t)16 * g.K;
    ushort* lAh0 = &sAh[(wave * 32) * 32];  ushort* lAh1 = &sAh[(wave * 32 + 16) * 32];
    ushort* lAl0 = &sAl[(wave * 32) * 32];  ushort* lAl1 = &sAl[(wave * 32 + 16) * 32];
    ushort* lBh0 = &sBh[(wave * 32) * 32];  ushort* lBh1 = &sBh[(wave * 32 + 16) * 32];
    ushort* lBl0 = &sBl[(wave * 32) * 32];  ushort* lBl1 = &sBl[(wave * 32 + 16) * 32];

    int aoff[4], boff[4];
#pragma unroll
    for (int i = 0; i < 4; i++) {
        aoff[i] = (wm + i * 16 + lm) * 32 + quad * 8;
        boff[i] = (wn + i * 16 + lm) * 32 + quad * 8;
    }

    f32x4 acc[4][4] = {};

    for (int k0 = 0; k0 < g.K; k0 += 32) {
        gl_lds16(gAh + k0, lAh0);  gl_lds16(gAh + rstepA + k0, lAh1);
        gl_lds16(gAl + k0, lAl0);  gl_lds16(gAl + rstepA + k0, lAl1);
        gl_lds16(gBh + k0, lBh0);  gl_lds16(gBh + rstepB + k0, lBh1);
        gl_lds16(gBl + k0, lBl0);  gl_lds16(gBl + rstepB + k0, lBl1);
        __syncthreads();

        bf16x8 ah[4], al[4], bh[4], bl[4];
#pragma unroll
        for (int i = 0; i < 4; i++) {
            ah[i] = *(const bf16x8*)&sAh[aoff[i]];
            al[i] = *(const bf16x8*)&sAl[aoff[i]];
            bh[i] = *(const bf16x8*)&sBh[boff[i]];
            bl[i] = *(const bf16x8*)&sBl[boff[i]];
        }
#pragma unroll
        for (int i = 0; i < 4; i++)
#pragma unroll
            for (int j = 0; j < 4; j++) {
                acc[i][j] = __builtin_amdgcn_mfma_f32_16x16x32_bf16(ah[i], bh[j], acc[i][j], 0, 0, 0);
                acc[i][j] = __builtin_amdgcn_mfma_f32_16x16x32_bf16(ah[i], bl[j], acc[i][j], 0, 0, 0);
                acc[i][j] = __builtin_amdgcn_mfma_f32_16x16x32_bf16(al[i], bh[j], acc[i][j], 0, 0, 0);
            }
        __syncthreads();
    }

    // epilogue: C/D layout col=lane&15, row=quad*4+reg
#pragma unroll
    for (int j = 0; j < 4; j++) {
        const int col = bn + wn + j * 16 + lm;
        if (col < g.Nreal) {
            const float bv = g.bias[col];
#pragma unroll
            for (int i = 0; i < 4; i++) {
#pragma unroll
                for (int r = 0; r < 4; r++) {
                    const int row = bm + wm + i * 16 + quad * 4 + r;
                    float v = acc[i][j][r] + bv;
                    if (g.mode == 1) {
                        v = fmaxf(v, 0.f);
                        ushort h, l;
                        split1(v, h, l);
                        g.Ch[(size_t)row * g.ldc + col] = h;
                        g.Cl[(size_t)row * g.ldc + col] = l;
                    } else {
                        g.Cf[(size_t)row * g.ldc + col] = v;
                    }
                }
            }
        }
    }
}

// ------------- per-row softmax stats (compact rows) -------------
__global__ void softmax_stats(const float* __restrict__ Z, int ncols,
                              const int* __restrict__ mc,
                              float* __restrict__ mx, float* __restrict__ sm)
{
    const int r = blockIdx.x;
    if (r >= mc[0]) return;
    const float* row = Z + (size_t)r * ncols;
    __shared__ float red[256];
    float m = -INFINITY;
    for (int c = threadIdx.x; c < ncols; c += 256) m = fmaxf(m, row[c]);
    red[threadIdx.x] = m;
    __syncthreads();
    for (int s = 128; s > 0; s >>= 1) {
        if (threadIdx.x < s) red[threadIdx.x] = fmaxf(red[threadIdx.x], red[threadIdx.x + s]);
        __syncthreads();
    }
    m = red[0];
    __syncthreads();
    float su = 0.f;
    for (int c = threadIdx.x; c < ncols; c += 256) su += expf(row[c] - m);
    red[threadIdx.x] = su;
    __syncthreads();
    for (int s = 128; s > 0; s >>= 1) {
        if (threadIdx.x < s) red[threadIdx.x] += red[threadIdx.x + s];
        __syncthreads();
    }
    if (threadIdx.x == 0) { mx[r] = m; sm[r] = red[0]; }
}

// ------------- per-label argmax over n of p_obj * p_att (compact rows) -------------
__global__ void argmax_kernel(
    const float* __restrict__ Zo, const float* __restrict__ Za,
    const float* __restrict__ mxo, const float* __restrict__ smo,
    const float* __restrict__ mxa, const float* __restrict__ sma,
    const int* __restrict__ label_img, const int* __restrict__ num_descs,
    const int* __restrict__ obj_labels, const int* __restrict__ att_labels,
    const int* __restrict__ off, int* __restrict__ desc)
{
    const int l = blockIdx.x;
    const int b = label_img[l];
    const int oc = obj_labels[l];
    const int ac = att_labels[l];
    const int nd = num_descs[b];
    const int r0 = off[b];
    const int n = threadIdx.x;   // blockDim 128

    float score = -INFINITY;
    if (n < Nq && n < nd) {
        const int r = r0 + n;
        const float po = expf(Zo[(size_t)r * Oq + oc] - mxo[r]) / smo[r];
        const float pa = expf(Za[(size_t)r * Aq + ac] - mxa[r]) / sma[r];
        score = po * pa;
    }
    __shared__ float ss[128];
    __shared__ int   si[128];
    ss[n] = score;
    si[n] = n;
    __syncthreads();
    for (int s = 64; s > 0; s >>= 1) {
        if (n < s) {
            const float s2 = ss[n + s];
            const int   i2 = si[n + s];
            if (s2 > ss[n] || (s2 == ss[n] && i2 < si[n])) { ss[n] = s2; si[n] = i2; }
        }
        __syncthreads();
    }
    if (n == 0) desc[l] = si[0];
}

// ------------- gather output rows: softmax(z[off[b]+desc, :]) -------------
__global__ void gather_out(
    const float* __restrict__ Zo, const float* __restrict__ Za,
    const float* __restrict__ mxo, const float* __restrict__ smo,
    const float* __restrict__ mxa, const float* __restrict__ sma,
    const int* __restrict__ label_img, const int* __restrict__ off,
    const int* __restrict__ desc, float* __restrict__ out)
{
    const int l = blockIdx.x;
    const int b = label_img[l];
    const int r = off[b] + desc[l];

    const float mo = mxo[r], so = smo[r];
    const float* zo = Zo + (size_t)r * Oq;
    float* oo = out + (size_t)l * Oq;
    for (int c = threadIdx.x; c < Oq; c += blockDim.x)
        oo[c] = expf(zo[c] - mo) / so;

    const float ma = mxa[r], sa = sma[r];
    const float* za = Za + (size_t)r * Aq;
    float* oa = out + (size_t)Lq * Oq + (size_t)l * Aq;
    for (int c = threadIdx.x; c < Aq; c += blockDim.x)
        oa[c] = expf(za[c] - ma) / sa;
}

extern "C" void kernel_launch(void* const* d_in, const int* in_sizes, int n_in,
                              void* d_out, int out_size, void* d_ws, size_t ws_size,
                              hipStream_t stream)
{
    const float* x          = (const float*)d_in[0];
    const int*   num_descs  = (const int*)d_in[1];
    const int*   label_img  = (const int*)d_in[2];
    const int*   obj_labels = (const int*)d_in[3];
    const int*   att_labels = (const int*)d_in[4];
    const float* w1o = (const float*)d_in[5];  const float* b1o = (const float*)d_in[6];
    const float* w2o = (const float*)d_in[7];  const float* b2o = (const float*)d_in[8];
    const float* w3o = (const float*)d_in[9];  const float* b3o = (const float*)d_in[10];
    const float* w1a = (const float*)d_in[11]; const float* b1a = (const float*)d_in[12];
    const float* w2a = (const float*)d_in[13]; const float* b2a = (const float*)d_in[14];
    const float* w3a = (const float*)d_in[15]; const float* b3a = (const float*)d_in[16];
    float* out = (float*)d_out;

    // ---- workspace carve with lifetime-based aliasing ----
    // bufA: xh|xl (L1 inputs)      -> later h2{o,a}{h,l}
    // bufB: h1{o,a}{h,l}           -> later z3o|z3a
    char* p = (char*)d_ws;
    auto carve = [&](size_t bytes) { char* q = p; p += (bytes + 255) & ~(size_t)255; return q; };

    char* bufA = carve((size_t)Mq * Dq * 2 * 2);            // 104.9 MB
    char* bufB = carve((size_t)Mq * Hq * 2 * 2 * 2);        // 104.9 MB
    ushort* w1oth = (ushort*)carve((size_t)Hq * Dq * 2);  ushort* w1otl = (ushort*)carve((size_t)Hq * Dq * 2);
    ushort* w1ath = (ushort*)carve((size_t)Hq * Dq * 2);  ushort* w1atl = (ushort*)carve((size_t)Hq * Dq * 2);
    ushort* w2oth = (ushort*)carve((size_t)Hq * Hq * 2);  ushort* w2otl = (ushort*)carve((size_t)Hq * Hq * 2);
    ushort* w2ath = (ushort*)carve((size_t)Hq * Hq * 2);  ushort* w2atl = (ushort*)carve((size_t)Hq * Hq * 2);
    ushort* w3oth = (ushort*)carve((size_t)OqP * Hq * 2); ushort* w3otl = (ushort*)carve((size_t)OqP * Hq * 2);
    ushort* w3ath = (ushort*)carve((size_t)AqP * Hq * 2); ushort* w3atl = (ushort*)carve((size_t)AqP * Hq * 2);
    float* mxo = (float*)carve(Mq * 4); float* smo = (float*)carve(Mq * 4);
    float* mxa = (float*)carve(Mq * 4); float* sma = (float*)carve(Mq * 4);
    int* desc   = (int*)carve(Lq * 4);
    int* off    = (int*)carve(Bq * 4);
    int* mc     = (int*)carve(2 * 4);
    int* rowmap = (int*)carve(Mq * 4);

    // aliased views
    ushort* xh = (ushort*)bufA;
    ushort* xl = xh + (size_t)Mq * Dq;
    ushort* h2oh = (ushort*)bufA;                    // after L1 consumed x? (x dead after L1)
    ushort* h2ol = h2oh + (size_t)Mq * Hq;
    ushort* h2ah = h2ol + (size_t)Mq * Hq;
    ushort* h2al = h2ah + (size_t)Mq * Hq;
    ushort* h1oh = (ushort*)bufB;
    ushort* h1ol = h1oh + (size_t)Mq * Hq;
    ushort* h1ah = h1ol + (size_t)Mq * Hq;
    ushort* h1al = h1ah + (size_t)Mq * Hq;
    float* z3o = (float*)bufB;                       // after L2 consumed h1
    float* z3a = z3o + (size_t)Mq * Oq;

    // ---- preprocessing ----
    build_offsets<<<1, 128, 0, stream>>>(num_descs, off, mc, rowmap);
    split_compact<<<(int)((size_t)Mq * Dq / 8 / 256), 256, 0, stream>>>(x, rowmap, mc, xh, xl);
    tsplit<<<dim3(Hq / 32, Dq / 32), 256, 0, stream>>>(w1o, w1oth, w1otl, Dq, Hq);
    tsplit<<<dim3(Hq / 32, Dq / 32), 256, 0, stream>>>(w1a, w1ath, w1atl, Dq, Hq);
    tsplit<<<dim3(Hq / 32, Hq / 32), 256, 0, stream>>>(w2o, w2oth, w2otl, Hq, Hq);
    tsplit<<<dim3(Hq / 32, Hq / 32), 256, 0, stream>>>(w2a, w2ath, w2atl, Hq, Hq);
    tsplit<<<dim3(OqP / 32, Hq / 32), 256, 0, stream>>>(w3o, w3oth, w3otl, Hq, Oq);
    tsplit<<<dim3(AqP / 32, Hq / 32), 256, 0, stream>>>(w3a, w3ath, w3atl, Hq, Aq);

    // ---- L1: h1 = relu(x @ w1 + b1), both branches fused (z) ----
    {
        GArgs go = { xh, xl, w1oth, w1otl, b1o, nullptr, h1oh, h1ol, Dq, Hq, Hq, Dq, Hq, 1 };
        GArgs ga = { xh, xl, w1ath, w1atl, b1a, nullptr, h1ah, h1al, Dq, Hq, Hq, Dq, Hq, 1 };
        gemm_split<<<dim3(Hq / 128, Mq / 128, 2), 256, 0, stream>>>(go, ga, mc);
    }
    // ---- L2: h2 = relu(h1 @ w2 + b2) ----  (writes into bufA; x is dead)
    {
        GArgs go = { h1oh, h1ol, w2oth, w2otl, b2o, nullptr, h2oh, h2ol, Hq, Hq, Hq, Hq, Hq, 1 };
        GArgs ga = { h1ah, h1al, w2ath, w2atl, b2a, nullptr, h2ah, h2al, Hq, Hq, Hq, Hq, Hq, 1 };
        gemm_split<<<dim3(Hq / 128, Mq / 128, 2), 256, 0, stream>>>(go, ga, mc);
    }
    // ---- L3: z3 = h2 @ w3 + b3 (fp32 out, writes into bufB; h1 is dead) ----
    {
        GArgs go = { h2oh, h2ol, w3oth, w3otl, b3o, z3o, nullptr, nullptr, Hq, OqP, Oq, Hq, Oq, 0 };
        GArgs ga = { h2ah, h2al, w3ath, w3atl, b3a, z3a, nullptr, nullptr, Hq, AqP, Aq, Hq, Aq, 0 };
        gemm_split<<<dim3(OqP / 128, Mq / 128, 2), 256, 0, stream>>>(go, ga, mc);
    }

    // ---- epilogue ----
    softmax_stats<<<Mq, 256, 0, stream>>>(z3o, Oq, mc, mxo, smo);
    softmax_stats<<<Mq, 256, 0, stream>>>(z3a, Aq, mc, mxa, sma);
    argmax_kernel<<<Lq, 128, 0, stream>>>(z3o, z3a, mxo, smo, mxa, sma,
                                          label_img, num_descs, obj_labels, att_labels, off, desc);
    gather_out<<<Lq, 256, 0, stream>>>(z3o, z3a, mxo, smo, mxa, sma,
                                       label_img, off, desc, out);
}